// Round 2
// 381.805 us; speedup vs baseline: 1.0221x; 1.0221x over previous
//
#include <hip/hip_runtime.h>

typedef unsigned short u16;
typedef short bf16x8 __attribute__((ext_vector_type(8)));
typedef float f32x4 __attribute__((ext_vector_type(4)));

#define DEV __device__ __forceinline__

DEV float b2f(u16 u) { union { unsigned i; float f; } x; x.i = ((unsigned)u) << 16; return x.f; }
DEV u16 f2b(float f) {
  union { float f; unsigned i; } x; x.f = f;
  unsigned r = x.i + 0x7fffu + ((x.i >> 16) & 1u);
  return (u16)(r >> 16);
}

DEV float exp2g(float x) { return __builtin_amdgcn_exp2f(x); }

#define GLDS(gp, lp) __builtin_amdgcn_global_load_lds( \
    (const __attribute__((address_space(1))) void*)(gp), \
    (__attribute__((address_space(3))) void*)(lp), 16, 0, 0)

// Q pre-scale: 80^-0.5 * log2(e)  (softmax done in exp2 domain)
constexpr float QSCALE = 0.11180339887498949f * 1.4426950408889634f;

// ---------------- prep: cvt hidden -> bf16  +  transpose w_qkv ----------------
__global__ __launch_bounds__(256) void prep_k(const float* __restrict__ hidden,
    u16* __restrict__ Ah, const float* __restrict__ wq, u16* __restrict__ Btq)
{
  __shared__ u16 tile[64 * 40];
  int b = blockIdx.x, tid = threadIdx.x;
  if (b < 5120) {
    int i = (b * 256 + tid) * 8;
    f32x4 a = *(const f32x4*)(hidden + i);
    f32x4 c = *(const f32x4*)(hidden + i + 4);
    bf16x8 o;
#pragma unroll
    for (int j = 0; j < 4; ++j) { o[j] = (short)f2b(a[j]); o[4 + j] = (short)f2b(c[j]); }
    *(bf16x8*)(Ah + i) = o;
  } else {
    int tb = b - 5120;                 // 2400 blocks: 60 x 40
    int bx = tb % 60, by = tb / 60;
    const int Kd = 1280, Nd = 3840;
    int k0 = by * 32, n0 = bx * 64;
#pragma unroll
    for (int t = 0; t < 2; ++t) {
      int c = t * 256 + tid;
      int k_l = c >> 4, n_l = (c & 15) << 2;
      f32x4 vv = *(const f32x4*)(wq + (size_t)(k0 + k_l) * Nd + n0 + n_l);
#pragma unroll
      for (int j = 0; j < 4; ++j) tile[(n_l + j) * 40 + k_l] = f2b(vv[j]);
    }
    __syncthreads();
    int n_l = tid >> 2, kc = (tid & 3) << 3;
    bf16x8 vv = *(const bf16x8*)(tile + n_l * 40 + kc);
    *(bf16x8*)(Btq + (size_t)(n0 + n_l) * Kd + k0 + kc) = vv;
  }
}

// ---------------- GEMM: C = A(MxK,bf16) @ Bt(NxK,bf16)^T + bias ----------------
// BK=64. LDS unpadded, XOR-swizzled on the SOURCE address (GLDS dest must be
// lane-linear): chunk j of row r lives at physical chunk j ^ (r&7).
// MODE 0: scatter bf16 Q/K[v][h][p][80], V^T[v][h][d][2048]; skip K/V blocks
// fully beyond valid len (masked keys -> exp2(-1e9)=0; 0xAA poison is finite).
template<int MODE>
__global__ __launch_bounds__(256) void gemm_k(const u16* __restrict__ A,
    const u16* __restrict__ Bt, const float* __restrict__ bias,
    u16* __restrict__ Oq, u16* __restrict__ Ok, u16* __restrict__ Ov,
    float* __restrict__ Of, const int* __restrict__ lens, int M, int N, int K)
{
  __shared__ u16 Asm[128 * 64];
  __shared__ u16 Bsm[128 * 64];
  const int tid = threadIdx.x;
  const int w = tid >> 6, lane = tid & 63, quad = lane >> 4, l16 = lane & 15;
  const int wm = w >> 1, wn = w & 1;
  const int m0 = blockIdx.y * 128, n0 = blockIdx.x * 128;

  if (MODE == 0) {
    if (n0 >= 1280) {                 // K/V output region
      int vv = m0 >> 11, p0 = m0 & 2047;
      int len = lens[vv]; if (len < 1) len = 1;
      if (p0 >= len) return;          // uniform: whole tile past valid keys
    }
  }

  // staging: 4 GLDS per matrix; chunk c = g*256+tid -> row c>>3, pc c&7
  const int srow = tid >> 3, spc = tid & 7;

  const f32x4 zero4 = {0.f, 0.f, 0.f, 0.f};
  f32x4 acc[4][4];
#pragma unroll
  for (int i = 0; i < 4; ++i)
#pragma unroll
    for (int j = 0; j < 4; ++j) acc[i][j] = zero4;

  for (int k0 = 0; k0 < K; k0 += 64) {
    __syncthreads();
#pragma unroll
    for (int g = 0; g < 4; ++g) {
      int r = g * 32 + srow;
      int q = spc ^ (r & 7);
      GLDS(A + (size_t)(m0 + r) * K + k0 + q * 8, Asm + r * 64 + spc * 8);
      GLDS(Bt + (size_t)(n0 + r) * K + k0 + q * 8, Bsm + r * 64 + spc * 8);
    }
    __syncthreads();
#pragma unroll
    for (int ks = 0; ks < 2; ++ks) {
      bf16x8 af[4], bfr[4];
#pragma unroll
      for (int mi = 0; mi < 4; ++mi) {
        int lr = wm * 64 + mi * 16 + l16;
        int ph = (ks * 4 + quad) ^ (lr & 7);
        af[mi] = *(const bf16x8*)(Asm + lr * 64 + ph * 8);
      }
#pragma unroll
      for (int ni = 0; ni < 4; ++ni) {
        int nr = wn * 64 + ni * 16 + l16;
        int ph = (ks * 4 + quad) ^ (nr & 7);
        bfr[ni] = *(const bf16x8*)(Bsm + nr * 64 + ph * 8);
      }
#pragma unroll
      for (int mi = 0; mi < 4; ++mi)
#pragma unroll
        for (int ni = 0; ni < 4; ++ni)
          acc[mi][ni] = __builtin_amdgcn_mfma_f32_16x16x32_bf16(af[mi], bfr[ni], acc[mi][ni], 0, 0, 0);
    }
  }

#pragma unroll
  for (int mi = 0; mi < 4; ++mi) {
#pragma unroll
    for (int ni = 0; ni < 4; ++ni) {
      int n = n0 + wn * 64 + ni * 16 + l16;
      float bb = bias[n];
#pragma unroll
      for (int r = 0; r < 4; ++r) {
        int m = m0 + wm * 64 + mi * 16 + quad * 4 + r;
        float val = acc[mi][ni][r] + bb;
        if (MODE == 0) {
          int t = n / 1280, rr = n - t * 1280;
          int hh = rr / 80, dd = rr - hh * 80;
          int vv = m >> 11, p = m & 2047;
          int vh = vv * 16 + hh;
          if (t == 0)      Oq[(size_t)(vh * 2048 + p) * 80 + dd] = f2b(val);
          else if (t == 1) Ok[(size_t)(vh * 2048 + p) * 80 + dd] = f2b(val);
          else             Ov[((size_t)vh * 80 + dd) * 2048 + p] = f2b(val);
        } else {
          Of[(size_t)m * N + n] = val;
        }
      }
    }
  }
}

// -------- RoPE (in place on Q,K stride 80; QSCALE into Q)  +  w_proj transpose ----
__global__ __launch_bounds__(256) void rope_proj_k(u16* __restrict__ Q, u16* __restrict__ K,
    const float* __restrict__ rope, const float* __restrict__ wp, u16* __restrict__ Btp)
{
  __shared__ u16 tile[64 * 40];
  int b = blockIdx.x, tid = threadIdx.x;
  if (b < 40960) {
    constexpr int TOT = 4 * 16 * 2048 * 40;
    int idx = b * 256 + tid;
    int which = idx >= TOT ? 1 : 0;
    int r = which ? idx - TOT : idx;
    int d = r % 40;
    int t1 = r / 40;
    int p = t1 & 2047;
    int vv = t1 >> 15;
    u16* buf = which ? K : Q;
    size_t base = (size_t)t1 * 80;
    int rc = (vv * 2048 + p) * 160;
    float x0 = b2f(buf[base + d]), x1 = b2f(buf[base + d + 40]);
    float c0 = rope[rc + d], c1 = rope[rc + d + 40];
    float s0 = rope[rc + 80 + d], s1 = rope[rc + 80 + d + 40];
    float y0 = x0 * c0 - x1 * s0;
    float y1 = x1 * c1 + x0 * s1;
    if (!which) { y0 *= QSCALE; y1 *= QSCALE; }
    buf[base + d] = f2b(y0);
    buf[base + d + 40] = f2b(y1);
  } else {
    int tb = b - 40960;                // 800 blocks: 20 x 40
    int bx = tb % 20, by = tb / 20;
    const int Kd = 1280, Nd = 1280;
    int k0 = by * 32, n0 = bx * 64;
#pragma unroll
    for (int t = 0; t < 2; ++t) {
      int c = t * 256 + tid;
      int k_l = c >> 4, n_l = (c & 15) << 2;
      f32x4 vv = *(const f32x4*)(wp + (size_t)(k0 + k_l) * Nd + n0 + n_l);
#pragma unroll
      for (int j = 0; j < 4; ++j) tile[(n_l + j) * 40 + k_l] = f2b(vv[j]);
    }
    __syncthreads();
    int n_l = tid >> 2, kc = (tid & 3) << 3;
    bf16x8 vv = *(const bf16x8*)(tile + n_l * 40 + kc);
    *(bf16x8*)(Btp + (size_t)(n0 + n_l) * Kd + k0 + kc) = vv;
  }
}

// ---------------- Flash attention ----------------
// P path: proven layout Psm[w][q*72+key]; conversion via v_cvt_pk_bf16_f32
// (2 instrs + 2 shifts per ni instead of 4x 5-op manual RTNE).
__global__ __launch_bounds__(256) void attn_k(const u16* __restrict__ Q,
    const u16* __restrict__ K, const u16* __restrict__ V,
    const int* __restrict__ lens, u16* __restrict__ O, const u16* __restrict__ zbuf)
{
  __shared__ u16 Ksm[64 * 96];
  __shared__ u16 Vt[96 * 64];
  __shared__ u16 Psm[4][16 * 72];
  const int v = blockIdx.z, h = blockIdx.y, q0 = blockIdx.x * 64;
  const int tid = threadIdx.x, w = tid >> 6, lane = tid & 63;
  const int quad = lane >> 4, l16 = lane & 15;
  int len = lens[v]; if (len < 1) len = 1;
  const int vh = v * 16 + h;

  // init Vt rows 80..95 once: d=80 -> 1.0, d=81..95 -> 0 (swizzle-invariant)
  if (tid < 128) {
    int row = 80 + (tid >> 3), pc = tid & 7;
    short val = (row == 80) ? (short)0x3F80 : (short)0;
    bf16x8 v8 = {val, val, val, val, val, val, val, val};
    *(bf16x8*)(Vt + row * 64 + pc * 8) = v8;
  }

  const bf16x8 zero8 = {0, 0, 0, 0, 0, 0, 0, 0};
  bf16x8 qf[3];
  {
    const u16* qp = Q + (size_t)(vh * 2048 + q0 + w * 16 + l16) * 80 + quad * 8;
    qf[0] = *(const bf16x8*)(qp);
    qf[1] = *(const bf16x8*)(qp + 32);
    qf[2] = (quad < 2) ? *(const bf16x8*)(qp + 64) : zero8;
  }

  const u16* kp[3]; int kstr[3];
#pragma unroll
  for (int t = 0; t < 3; ++t) {
    int L = w * 192 + t * 64 + lane;
    int key = L / 12, pc = L - key * 12;
    int q = (pc < 8) ? (pc ^ (key & 7)) : (8 + ((pc - 8) ^ (key & 3)));
    bool valid = q < 10;
    kp[t] = valid ? (K + (size_t)(vh * 2048 + key) * 80 + q * 8) : zbuf;
    kstr[t] = valid ? 5120 : 0;
  }
  const u16* vp[3];
#pragma unroll
  for (int t = 0; t < 3; ++t) {
    int seg = w + t * 4;
    int d = seg * 8 + (lane >> 3), pc = lane & 7;
    int q = pc ^ (d & 7);
    vp[t] = V + ((size_t)vh * 80 + d) * 2048 + q * 8;
  }

  const f32x4 zero4 = {0.f, 0.f, 0.f, 0.f};
  f32x4 o[6];
#pragma unroll
  for (int i = 0; i < 6; ++i) o[i] = zero4;
  float m_run[4] = {-3e38f, -3e38f, -3e38f, -3e38f};

  for (int key0 = 0; key0 < len; key0 += 64) {
    __syncthreads();
#pragma unroll
    for (int t = 0; t < 3; ++t) {
      GLDS(kp[t], Ksm + (w * 192 + t * 64) * 8);
      kp[t] += kstr[t];
    }
#pragma unroll
    for (int t = 0; t < 3; ++t) {
      int seg = w + t * 4;
      if (seg < 10) { GLDS(vp[t], Vt + seg * 512); vp[t] += 64; }
    }
    __syncthreads();

    f32x4 s[4];
#pragma unroll
    for (int i = 0; i < 4; ++i) s[i] = zero4;
    __builtin_amdgcn_s_setprio(1);
#pragma unroll
    for (int ks = 0; ks < 3; ++ks) {
      int ph = (ks < 2) ? ((ks * 4 + quad) ^ (l16 & 7)) : (8 + (quad ^ (l16 & 3)));
#pragma unroll
      for (int ni = 0; ni < 4; ++ni) {
        bf16x8 kb = *(const bf16x8*)(Ksm + (ni * 16 + l16) * 96 + ph * 8);
        s[ni] = __builtin_amdgcn_mfma_f32_16x16x32_bf16(qf[ks], kb, s[ni], 0, 0, 0);
      }
    }
    __builtin_amdgcn_s_setprio(0);

    if (key0 + 64 > len) {             // uniform: only the last partial tile
#pragma unroll
      for (int ni = 0; ni < 4; ++ni) {
        int key = key0 + ni * 16 + l16;
        if (key >= len) {
#pragma unroll
          for (int r = 0; r < 4; ++r) s[ni][r] = -1e9f;
        }
      }
    }
    float mx[4];
#pragma unroll
    for (int r = 0; r < 4; ++r) mx[r] = fmaxf(fmaxf(s[0][r], s[1][r]), fmaxf(s[2][r], s[3][r]));
#pragma unroll
    for (int off = 1; off < 16; off <<= 1)
#pragma unroll
      for (int r = 0; r < 4; ++r) mx[r] = fmaxf(mx[r], __shfl_xor(mx[r], off, 64));

    // defer-max: only rescale when some row's max grew past threshold (2^8 headroom)
    int grow = (mx[0] > m_run[0] + 8.f) | (mx[1] > m_run[1] + 8.f) |
               (mx[2] > m_run[2] + 8.f) | (mx[3] > m_run[3] + 8.f);
    if (__any(grow)) {
      float alpha[4];
#pragma unroll
      for (int r = 0; r < 4; ++r) {
        float mn = fmaxf(m_run[r], mx[r]);
        alpha[r] = exp2g(m_run[r] - mn);
        m_run[r] = mn;
      }
#pragma unroll
      for (int ni = 0; ni < 6; ++ni)
#pragma unroll
        for (int r = 0; r < 4; ++r) o[ni][r] *= alpha[r];
    }

#pragma unroll
    for (int ni = 0; ni < 4; ++ni)
#pragma unroll
      for (int r = 0; r < 4; ++r) s[ni][r] = exp2g(s[ni][r] - m_run[r]);

    // pack P -> Psm[w][q*72 + key]: 2x cvt_pk + 2 shifts per ni (was 4x manual RTNE)
#pragma unroll
    for (int ni = 0; ni < 4; ++ni) {
      unsigned w0, w1;
      asm("v_cvt_pk_bf16_f32 %0, %1, %2" : "=v"(w0) : "v"(s[ni][0]), "v"(s[ni][1]));
      asm("v_cvt_pk_bf16_f32 %0, %1, %2" : "=v"(w1) : "v"(s[ni][2]), "v"(s[ni][3]));
      u16* pp = &Psm[w][ni * 16 + l16];
      pp[(quad * 4 + 0) * 72] = (u16)w0;
      pp[(quad * 4 + 1) * 72] = (u16)(w0 >> 16);
      pp[(quad * 4 + 2) * 72] = (u16)w1;
      pp[(quad * 4 + 3) * 72] = (u16)(w1 >> 16);
    }

    __builtin_amdgcn_s_setprio(1);
#pragma unroll
    for (int ks = 0; ks < 2; ++ks) {
      bf16x8 pa = *(const bf16x8*)(&Psm[w][l16 * 72 + ks * 32 + quad * 8]);
      int ph = (ks * 4 + quad) ^ (l16 & 7);
#pragma unroll
      for (int ni = 0; ni < 6; ++ni) {
        bf16x8 vb = *(const bf16x8*)(Vt + (ni * 16 + l16) * 64 + ph * 8);
        o[ni] = __builtin_amdgcn_mfma_f32_16x16x32_bf16(pa, vb, o[ni], 0, 0, 0);
      }
    }
    __builtin_amdgcn_s_setprio(0);
  }
  float inv[4];
#pragma unroll
  for (int r = 0; r < 4; ++r) {
    float l = __shfl(o[5][r], (lane & 48), 64);
    inv[r] = 1.0f / l;
  }
#pragma unroll
  for (int ni = 0; ni < 5; ++ni)
#pragma unroll
    for (int r = 0; r < 4; ++r) {
      int qq = q0 + w * 16 + quad * 4 + r;
      O[((size_t)(v * 2048 + qq) * 16 + h) * 80 + ni * 16 + l16] = f2b(o[ni][r] * inv[r]);
    }
}

extern "C" void kernel_launch(void* const* d_in, const int* in_sizes, int n_in,
                              void* d_out, int out_size, void* d_ws, size_t ws_size,
                              hipStream_t stream) {
  const float* hidden = (const float*)d_in[0];
  const float* rope   = (const float*)d_in[1];
  const int*   lens   = (const int*)d_in[2];
  const float* w_qkv  = (const float*)d_in[3];
  const float* b_qkv  = (const float*)d_in[4];
  const float* w_proj = (const float*)d_in[5];
  const float* b_proj = (const float*)d_in[6];
  float* out = (float*)d_out;
  char* ws = (char*)d_ws;
  u16* Ah = (u16*)(ws);
  u16* Bt = (u16*)(ws + 20971520);
  u16* Qb = (u16*)(ws + 30801920);
  u16* Kb = (u16*)(ws + 51773440);
  u16* Vb = (u16*)(ws + 72744960);
  u16* At = Ah;
  u16* Bp = Bt;

  prep_k<<<7520, 256, 0, stream>>>(hidden, Ah, w_qkv, Bt);
  gemm_k<0><<<dim3(30, 64), 256, 0, stream>>>(Ah, Bt, b_qkv, Qb, Kb, Vb, nullptr, lens, 8192, 3840, 1280);
  rope_proj_k<<<41760, 256, 0, stream>>>(Qb, Kb, rope, w_proj, Bp);
  attn_k<<<dim3(32, 16, 4), 256, 0, stream>>>(Qb, Kb, Vb, lens, At, (const u16*)b_qkv);
  gemm_k<1><<<dim3(10, 64), 256, 0, stream>>>(At, Bp, b_proj, nullptr, nullptr, nullptr, out, lens, 8192, 1280, 1280);
}

// Round 3
// 371.743 us; speedup vs baseline: 1.0497x; 1.0271x over previous
//
#include <hip/hip_runtime.h>

typedef unsigned short u16;
typedef short bf16x8 __attribute__((ext_vector_type(8)));
typedef float f32x4 __attribute__((ext_vector_type(4)));

#define DEV __device__ __forceinline__

DEV float b2f(u16 u) { union { unsigned i; float f; } x; x.i = ((unsigned)u) << 16; return x.f; }
DEV u16 f2b(float f) {
  union { float f; unsigned i; } x; x.f = f;
  unsigned r = x.i + 0x7fffu + ((x.i >> 16) & 1u);
  return (u16)(r >> 16);
}

DEV float exp2g(float x) { return __builtin_amdgcn_exp2f(x); }

// DPP max step: fold in value from another lane of the 16-lane row.
// 0xB1=quad_perm[1,0,3,2] (xor1), 0x4E=quad_perm[2,3,0,1] (xor2),
// 0x124=row_ror:4, 0x128=row_ror:8. Order-insensitive for max.
template<int CTRL>
DEV float dppmax(float x) {
  int t = __builtin_amdgcn_update_dpp(__builtin_bit_cast(int, x),
                                      __builtin_bit_cast(int, x), CTRL, 0xf, 0xf, false);
  return fmaxf(x, __builtin_bit_cast(float, t));
}

#define GLDS(gp, lp) __builtin_amdgcn_global_load_lds( \
    (const __attribute__((address_space(1))) void*)(gp), \
    (__attribute__((address_space(3))) void*)(lp), 16, 0, 0)

// Q pre-scale: 80^-0.5 * log2(e)  (softmax done in exp2 domain)
constexpr float QSCALE = 0.11180339887498949f * 1.4426950408889634f;

// ---------------- prep: cvt hidden -> bf16  +  transpose w_qkv ----------------
__global__ __launch_bounds__(256) void prep_k(const float* __restrict__ hidden,
    u16* __restrict__ Ah, const float* __restrict__ wq, u16* __restrict__ Btq)
{
  __shared__ u16 tile[64 * 40];
  int b = blockIdx.x, tid = threadIdx.x;
  if (b < 5120) {
    int i = (b * 256 + tid) * 8;
    f32x4 a = *(const f32x4*)(hidden + i);
    f32x4 c = *(const f32x4*)(hidden + i + 4);
    bf16x8 o;
#pragma unroll
    for (int j = 0; j < 4; ++j) { o[j] = (short)f2b(a[j]); o[4 + j] = (short)f2b(c[j]); }
    *(bf16x8*)(Ah + i) = o;
  } else {
    int tb = b - 5120;                 // 2400 blocks: 60 x 40
    int bx = tb % 60, by = tb / 60;
    const int Kd = 1280, Nd = 3840;
    int k0 = by * 32, n0 = bx * 64;
#pragma unroll
    for (int t = 0; t < 2; ++t) {
      int c = t * 256 + tid;
      int k_l = c >> 4, n_l = (c & 15) << 2;
      f32x4 vv = *(const f32x4*)(wq + (size_t)(k0 + k_l) * Nd + n0 + n_l);
#pragma unroll
      for (int j = 0; j < 4; ++j) tile[(n_l + j) * 40 + k_l] = f2b(vv[j]);
    }
    __syncthreads();
    int n_l = tid >> 2, kc = (tid & 3) << 3;
    bf16x8 vv = *(const bf16x8*)(tile + n_l * 40 + kc);
    *(bf16x8*)(Btq + (size_t)(n0 + n_l) * Kd + k0 + kc) = vv;
  }
}

// ---------------- GEMM: C = A(MxK,bf16) @ Bt(NxK,bf16)^T + bias ----------------
// BK=64. LDS unpadded, XOR-swizzled on the SOURCE address (GLDS dest must be
// lane-linear): chunk j of row r lives at physical chunk j ^ (r&7).
// MODE 0: scatter bf16 Q/K[v][h][p][80], V^T[v][h][d][2048]; skip K/V blocks
// fully beyond valid len (masked keys -> exp2(-1e9)=0; 0xAA poison is finite).
template<int MODE>
__global__ __launch_bounds__(256) void gemm_k(const u16* __restrict__ A,
    const u16* __restrict__ Bt, const float* __restrict__ bias,
    u16* __restrict__ Oq, u16* __restrict__ Ok, u16* __restrict__ Ov,
    float* __restrict__ Of, const int* __restrict__ lens, int M, int N, int K)
{
  __shared__ u16 Asm[128 * 64];
  __shared__ u16 Bsm[128 * 64];
  const int tid = threadIdx.x;
  const int w = tid >> 6, lane = tid & 63, quad = lane >> 4, l16 = lane & 15;
  const int wm = w >> 1, wn = w & 1;
  const int m0 = blockIdx.y * 128, n0 = blockIdx.x * 128;

  if (MODE == 0) {
    if (n0 >= 1280) {                 // K/V output region
      int vv = m0 >> 11, p0 = m0 & 2047;
      int len = lens[vv]; if (len < 1) len = 1;
      if (p0 >= len) return;          // uniform: whole tile past valid keys
    }
  }

  // staging: 4 GLDS per matrix; chunk c = g*256+tid -> row c>>3, pc c&7
  const int srow = tid >> 3, spc = tid & 7;

  const f32x4 zero4 = {0.f, 0.f, 0.f, 0.f};
  f32x4 acc[4][4];
#pragma unroll
  for (int i = 0; i < 4; ++i)
#pragma unroll
    for (int j = 0; j < 4; ++j) acc[i][j] = zero4;

  for (int k0 = 0; k0 < K; k0 += 64) {
    __syncthreads();
#pragma unroll
    for (int g = 0; g < 4; ++g) {
      int r = g * 32 + srow;
      int q = spc ^ (r & 7);
      GLDS(A + (size_t)(m0 + r) * K + k0 + q * 8, Asm + r * 64 + spc * 8);
      GLDS(Bt + (size_t)(n0 + r) * K + k0 + q * 8, Bsm + r * 64 + spc * 8);
    }
    __syncthreads();
#pragma unroll
    for (int ks = 0; ks < 2; ++ks) {
      bf16x8 af[4], bfr[4];
#pragma unroll
      for (int mi = 0; mi < 4; ++mi) {
        int lr = wm * 64 + mi * 16 + l16;
        int ph = (ks * 4 + quad) ^ (lr & 7);
        af[mi] = *(const bf16x8*)(Asm + lr * 64 + ph * 8);
      }
#pragma unroll
      for (int ni = 0; ni < 4; ++ni) {
        int nr = wn * 64 + ni * 16 + l16;
        int ph = (ks * 4 + quad) ^ (nr & 7);
        bfr[ni] = *(const bf16x8*)(Bsm + nr * 64 + ph * 8);
      }
#pragma unroll
      for (int mi = 0; mi < 4; ++mi)
#pragma unroll
        for (int ni = 0; ni < 4; ++ni)
          acc[mi][ni] = __builtin_amdgcn_mfma_f32_16x16x32_bf16(af[mi], bfr[ni], acc[mi][ni], 0, 0, 0);
    }
  }

#pragma unroll
  for (int mi = 0; mi < 4; ++mi) {
#pragma unroll
    for (int ni = 0; ni < 4; ++ni) {
      int n = n0 + wn * 64 + ni * 16 + l16;
      float bb = bias[n];
#pragma unroll
      for (int r = 0; r < 4; ++r) {
        int m = m0 + wm * 64 + mi * 16 + quad * 4 + r;
        float val = acc[mi][ni][r] + bb;
        if (MODE == 0) {
          int t = n / 1280, rr = n - t * 1280;
          int hh = rr / 80, dd = rr - hh * 80;
          int vv = m >> 11, p = m & 2047;
          int vh = vv * 16 + hh;
          if (t == 0)      Oq[(size_t)(vh * 2048 + p) * 80 + dd] = f2b(val);
          else if (t == 1) Ok[(size_t)(vh * 2048 + p) * 80 + dd] = f2b(val);
          else             Ov[((size_t)vh * 80 + dd) * 2048 + p] = f2b(val);
        } else {
          Of[(size_t)m * N + n] = val;
        }
      }
    }
  }
}

// -------- RoPE (vectorized bf16x8, in place on Q,K stride 80; QSCALE into Q)
// -------- + w_proj transpose ----
__global__ __launch_bounds__(256) void rope_proj_k(u16* __restrict__ Q, u16* __restrict__ K,
    const float* __restrict__ rope, const float* __restrict__ wp, u16* __restrict__ Btp)
{
  __shared__ u16 tile[64 * 40];
  int b = blockIdx.x, tid = threadIdx.x;
  if (b < 5120) {
    // 1,310,720 threads: 2 bufs x 131072 rows x 5 chunks of 8 d-values
    int idx = b * 256 + tid;
    int which = idx >= 655360 ? 1 : 0;
    int r = which ? idx - 655360 : idx;
    int row = r / 5, c = r - row * 5;
    int d0 = c * 8;
    int p = row & 2047, vv = row >> 15;
    u16* buf = which ? K : Q;
    size_t base = (size_t)row * 80;
    int rc = (vv * 2048 + p) * 160;
    bf16x8 x0 = *(const bf16x8*)(buf + base + d0);
    bf16x8 x1 = *(const bf16x8*)(buf + base + 40 + d0);
    f32x4 c0a = *(const f32x4*)(rope + rc + d0);
    f32x4 c0b = *(const f32x4*)(rope + rc + d0 + 4);
    f32x4 c1a = *(const f32x4*)(rope + rc + 40 + d0);
    f32x4 c1b = *(const f32x4*)(rope + rc + 44 + d0);
    f32x4 s0a = *(const f32x4*)(rope + rc + 80 + d0);
    f32x4 s0b = *(const f32x4*)(rope + rc + 84 + d0);
    f32x4 s1a = *(const f32x4*)(rope + rc + 120 + d0);
    f32x4 s1b = *(const f32x4*)(rope + rc + 124 + d0);
    float sc = which ? 1.0f : QSCALE;
    bf16x8 y0, y1;
#pragma unroll
    for (int j = 0; j < 8; ++j) {
      float xa = b2f((u16)x0[j]), xb = b2f((u16)x1[j]);
      float cc0 = j < 4 ? c0a[j & 3] : c0b[j & 3];
      float cc1 = j < 4 ? c1a[j & 3] : c1b[j & 3];
      float ss0 = j < 4 ? s0a[j & 3] : s0b[j & 3];
      float ss1 = j < 4 ? s1a[j & 3] : s1b[j & 3];
      y0[j] = (short)f2b((xa * cc0 - xb * ss0) * sc);
      y1[j] = (short)f2b((xb * cc1 + xa * ss1) * sc);
    }
    *(bf16x8*)(buf + base + d0) = y0;
    *(bf16x8*)(buf + base + 40 + d0) = y1;
  } else {
    int tb = b - 5120;                 // 800 blocks: 20 x 40
    int bx = tb % 20, by = tb / 20;
    const int Kd = 1280, Nd = 1280;
    int k0 = by * 32, n0 = bx * 64;
#pragma unroll
    for (int t = 0; t < 2; ++t) {
      int c = t * 256 + tid;
      int k_l = c >> 4, n_l = (c & 15) << 2;
      f32x4 vv = *(const f32x4*)(wp + (size_t)(k0 + k_l) * Nd + n0 + n_l);
#pragma unroll
      for (int j = 0; j < 4; ++j) tile[(n_l + j) * 40 + k_l] = f2b(vv[j]);
    }
    __syncthreads();
    int n_l = tid >> 2, kc = (tid & 3) << 3;
    bf16x8 vv = *(const bf16x8*)(tile + n_l * 40 + kc);
    *(bf16x8*)(Btp + (size_t)(n0 + n_l) * Kd + k0 + kc) = vv;
  }
}

// ---------------- Flash attention ----------------
// K/V reg-staged (T14): global_load_dwordx4 for tile t+1 issued during compute
// of tile t; ds_write_b128 to the SAME LDS bytes the old GLDS path used
// (GLDS dest = uniform base + lane*16B  <=>  ds_write at base + lane*8 u16).
// Softmax row-max via DPP (quad_perm xor1/xor2 + row_ror 4/8) — no LDS pipe.
__global__ __launch_bounds__(256) void attn_k(const u16* __restrict__ Q,
    const u16* __restrict__ K, const u16* __restrict__ V,
    const int* __restrict__ lens, u16* __restrict__ O, const u16* __restrict__ zbuf)
{
  __shared__ u16 Ksm[64 * 96];
  __shared__ u16 Vt[96 * 64];
  __shared__ u16 Psm[4][16 * 72];
  const int v = blockIdx.z, h = blockIdx.y, q0 = blockIdx.x * 64;
  const int tid = threadIdx.x, w = tid >> 6, lane = tid & 63;
  const int quad = lane >> 4, l16 = lane & 15;
  int len = lens[v]; if (len < 1) len = 1;
  const int vh = v * 16 + h;

  // init Vt rows 80..95 once: d=80 -> 1.0, d=81..95 -> 0 (swizzle-invariant)
  if (tid < 128) {
    int row = 80 + (tid >> 3), pc = tid & 7;
    short val = (row == 80) ? (short)0x3F80 : (short)0;
    bf16x8 v8 = {val, val, val, val, val, val, val, val};
    *(bf16x8*)(Vt + row * 64 + pc * 8) = v8;
  }

  const bf16x8 zero8 = {0, 0, 0, 0, 0, 0, 0, 0};
  bf16x8 qf[3];
  {
    const u16* qp = Q + (size_t)(vh * 2048 + q0 + w * 16 + l16) * 80 + quad * 8;
    qf[0] = *(const bf16x8*)(qp);
    qf[1] = *(const bf16x8*)(qp + 32);
    qf[2] = (quad < 2) ? *(const bf16x8*)(qp + 64) : zero8;
  }

  const u16* kp[3]; int kstr[3];
#pragma unroll
  for (int t = 0; t < 3; ++t) {
    int L = w * 192 + t * 64 + lane;
    int key = L / 12, pc = L - key * 12;
    int q = (pc < 8) ? (pc ^ (key & 7)) : (8 + ((pc - 8) ^ (key & 3)));
    bool valid = q < 10;
    kp[t] = valid ? (K + (size_t)(vh * 2048 + key) * 80 + q * 8) : zbuf;
    kstr[t] = valid ? 5120 : 0;
  }
  const u16* vp[3];
  bool vok[3];
#pragma unroll
  for (int t = 0; t < 3; ++t) {
    int seg = w + t * 4;
    int d = seg * 8 + (lane >> 3), pc = lane & 7;
    int q = pc ^ (d & 7);
    vp[t] = V + ((size_t)vh * 80 + d) * 2048 + q * 8;
    vok[t] = seg < 10;
  }

  f32x4 kreg[3], vreg[3];
#define ISSUE_KV() do { \
  _Pragma("unroll") \
  for (int t = 0; t < 3; ++t) { kreg[t] = *(const f32x4*)(kp[t]); kp[t] += kstr[t]; } \
  _Pragma("unroll") \
  for (int t = 0; t < 3; ++t) { if (vok[t]) { vreg[t] = *(const f32x4*)(vp[t]); vp[t] += 64; } } \
} while (0)
#define WRITE_KV() do { \
  _Pragma("unroll") \
  for (int t = 0; t < 3; ++t) *(f32x4*)(Ksm + (w * 192 + t * 64 + lane) * 8) = kreg[t]; \
  _Pragma("unroll") \
  for (int t = 0; t < 3; ++t) { if (vok[t]) *(f32x4*)(Vt + (w + t * 4) * 512 + lane * 8) = vreg[t]; } \
} while (0)

  const f32x4 zero4 = {0.f, 0.f, 0.f, 0.f};
  f32x4 o[6];
#pragma unroll
  for (int i = 0; i < 6; ++i) o[i] = zero4;
  float m_run[4] = {-3e38f, -3e38f, -3e38f, -3e38f};

  ISSUE_KV();                          // prefetch tile 0
  for (int key0 = 0; key0 < len; key0 += 64) {
    __syncthreads();                   // all waves done reading prev tile
    WRITE_KV();                        // regs -> LDS (compiler waits vmcnt via dep)
    __syncthreads();
    if (key0 + 64 < len) ISSUE_KV();   // prefetch next tile under compute

    f32x4 s[4];
#pragma unroll
    for (int i = 0; i < 4; ++i) s[i] = zero4;
    __builtin_amdgcn_s_setprio(1);
#pragma unroll
    for (int ks = 0; ks < 3; ++ks) {
      int ph = (ks < 2) ? ((ks * 4 + quad) ^ (l16 & 7)) : (8 + (quad ^ (l16 & 3)));
#pragma unroll
      for (int ni = 0; ni < 4; ++ni) {
        bf16x8 kb = *(const bf16x8*)(Ksm + (ni * 16 + l16) * 96 + ph * 8);
        s[ni] = __builtin_amdgcn_mfma_f32_16x16x32_bf16(qf[ks], kb, s[ni], 0, 0, 0);
      }
    }
    __builtin_amdgcn_s_setprio(0);

    if (key0 + 64 > len) {             // uniform: only the last partial tile
#pragma unroll
      for (int ni = 0; ni < 4; ++ni) {
        int key = key0 + ni * 16 + l16;
        if (key >= len) {
#pragma unroll
          for (int r = 0; r < 4; ++r) s[ni][r] = -1e9f;
        }
      }
    }
    float mx[4];
#pragma unroll
    for (int r = 0; r < 4; ++r) {
      mx[r] = fmaxf(fmaxf(s[0][r], s[1][r]), fmaxf(s[2][r], s[3][r]));
      mx[r] = dppmax<0xB1>(mx[r]);     // xor1 (quad_perm [1,0,3,2])
      mx[r] = dppmax<0x4E>(mx[r]);     // xor2 (quad_perm [2,3,0,1])
      mx[r] = dppmax<0x124>(mx[r]);    // row_ror:4
      mx[r] = dppmax<0x128>(mx[r]);    // row_ror:8
    }

    // defer-max: only rescale when some row's max grew past threshold (2^8 headroom)
    int grow = (mx[0] > m_run[0] + 8.f) | (mx[1] > m_run[1] + 8.f) |
               (mx[2] > m_run[2] + 8.f) | (mx[3] > m_run[3] + 8.f);
    if (__any(grow)) {
      float alpha[4];
#pragma unroll
      for (int r = 0; r < 4; ++r) {
        float mn = fmaxf(m_run[r], mx[r]);
        alpha[r] = exp2g(m_run[r] - mn);
        m_run[r] = mn;
      }
#pragma unroll
      for (int ni = 0; ni < 6; ++ni)
#pragma unroll
        for (int r = 0; r < 4; ++r) o[ni][r] *= alpha[r];
    }

#pragma unroll
    for (int ni = 0; ni < 4; ++ni)
#pragma unroll
      for (int r = 0; r < 4; ++r) s[ni][r] = exp2g(s[ni][r] - m_run[r]);

    // pack P -> Psm[w][q*72 + key]: 2x cvt_pk + 2 shifts per ni
#pragma unroll
    for (int ni = 0; ni < 4; ++ni) {
      unsigned w0, w1;
      asm("v_cvt_pk_bf16_f32 %0, %1, %2" : "=v"(w0) : "v"(s[ni][0]), "v"(s[ni][1]));
      asm("v_cvt_pk_bf16_f32 %0, %1, %2" : "=v"(w1) : "v"(s[ni][2]), "v"(s[ni][3]));
      u16* pp = &Psm[w][ni * 16 + l16];
      pp[(quad * 4 + 0) * 72] = (u16)w0;
      pp[(quad * 4 + 1) * 72] = (u16)(w0 >> 16);
      pp[(quad * 4 + 2) * 72] = (u16)w1;
      pp[(quad * 4 + 3) * 72] = (u16)(w1 >> 16);
    }

    __builtin_amdgcn_s_setprio(1);
#pragma unroll
    for (int ks = 0; ks < 2; ++ks) {
      bf16x8 pa = *(const bf16x8*)(&Psm[w][l16 * 72 + ks * 32 + quad * 8]);
      int ph = (ks * 4 + quad) ^ (l16 & 7);
#pragma unroll
      for (int ni = 0; ni < 6; ++ni) {
        bf16x8 vb = *(const bf16x8*)(Vt + (ni * 16 + l16) * 64 + ph * 8);
        o[ni] = __builtin_amdgcn_mfma_f32_16x16x32_bf16(pa, vb, o[ni], 0, 0, 0);
      }
    }
    __builtin_amdgcn_s_setprio(0);
  }
  float inv[4];
#pragma unroll
  for (int r = 0; r < 4; ++r) {
    float l = __shfl(o[5][r], (lane & 48), 64);
    inv[r] = 1.0f / l;
  }
#pragma unroll
  for (int ni = 0; ni < 5; ++ni)
#pragma unroll
    for (int r = 0; r < 4; ++r) {
      int qq = q0 + w * 16 + quad * 4 + r;
      O[((size_t)(v * 2048 + qq) * 16 + h) * 80 + ni * 16 + l16] = f2b(o[ni][r] * inv[r]);
    }
#undef ISSUE_KV
#undef WRITE_KV
}

extern "C" void kernel_launch(void* const* d_in, const int* in_sizes, int n_in,
                              void* d_out, int out_size, void* d_ws, size_t ws_size,
                              hipStream_t stream) {
  const float* hidden = (const float*)d_in[0];
  const float* rope   = (const float*)d_in[1];
  const int*   lens   = (const int*)d_in[2];
  const float* w_qkv  = (const float*)d_in[3];
  const float* b_qkv  = (const float*)d_in[4];
  const float* w_proj = (const float*)d_in[5];
  const float* b_proj = (const float*)d_in[6];
  float* out = (float*)d_out;
  char* ws = (char*)d_ws;
  u16* Ah = (u16*)(ws);
  u16* Bt = (u16*)(ws + 20971520);
  u16* Qb = (u16*)(ws + 30801920);
  u16* Kb = (u16*)(ws + 51773440);
  u16* Vb = (u16*)(ws + 72744960);
  u16* At = Ah;
  u16* Bp = Bt;

  prep_k<<<7520, 256, 0, stream>>>(hidden, Ah, w_qkv, Bt);
  gemm_k<0><<<dim3(30, 64), 256, 0, stream>>>(Ah, Bt, b_qkv, Qb, Kb, Vb, nullptr, lens, 8192, 3840, 1280);
  rope_proj_k<<<5920, 256, 0, stream>>>(Qb, Kb, rope, w_proj, Bp);
  attn_k<<<dim3(32, 16, 4), 256, 0, stream>>>(Qb, Kb, Vb, lens, At, (const u16*)b_qkv);
  gemm_k<1><<<dim3(10, 64), 256, 0, stream>>>(At, Bp, b_proj, nullptr, nullptr, nullptr, out, lens, 8192, 1280, 1280);
}